// Round 2
// baseline (1399.296 us; speedup 1.0000x reference)
//
#include <hip/hip_runtime.h>
#include <stdint.h>

#define SCALE 0.17677669529663687f  // 32^-0.5

typedef __attribute__((ext_vector_type(8))) short short8;
typedef __attribute__((ext_vector_type(4))) float floatx4;

__device__ __forceinline__ unsigned short f2bf(float f) {
    union { float f; unsigned u; } v; v.f = f;
    unsigned r = (v.u + 0x7fffu + ((v.u >> 16) & 1u)) >> 16;  // RNE
    return (unsigned short)r;
}

// ---------- prep: tiled transpose fp32 -> bf16, out[c][r] = bf16(in[r][c]) ----------
__global__ void transpose_bf16(const float* __restrict__ in, unsigned short* __restrict__ out,
                               int R, int Cc) {
    __shared__ float t[32][33];
    const int tx = threadIdx.x & 31, ty = threadIdx.x >> 5;  // 32x8
    const int c0 = blockIdx.x * 32, r0 = blockIdx.y * 32;
#pragma unroll
    for (int i = 0; i < 4; ++i) {
        int r = ty + i * 8;
        t[r][tx] = in[(size_t)(r0 + r) * Cc + c0 + tx];
    }
    __syncthreads();
#pragma unroll
    for (int i = 0; i < 4; ++i) {
        int rr = ty + i * 8;
        out[(size_t)(c0 + rr) * R + r0 + tx] = f2bf(t[tx][rr]);
    }
}

// ---------- prep: relative-position bias table bt[h][i][j], 12x64x64 fp32 ----------
__global__ void prep_bias(const float* __restrict__ w1, const float* __restrict__ b1,
                          const float* __restrict__ w2, const float* __restrict__ b2,
                          float* __restrict__ bt) {
    int t = blockIdx.x * 64 + threadIdx.x;  // 4096 threads over 64 blocks
    int i = t >> 6, j = t & 63;
    float r0 = (float)((i >> 4) - (j >> 4));
    float r1 = (float)(((i >> 2) & 3) - ((j >> 2) & 3));
    float r2 = (float)((i & 3) - (j & 3));
    float acc[12];
#pragma unroll
    for (int h = 0; h < 12; ++h) acc[h] = b2[h];
    for (int u = 0; u < 64; ++u) {
        float hv = r0 * w1[u] + r1 * w1[64 + u] + r2 * w1[128 + u] + b1[u];
        hv = fmaxf(hv, 0.f);
#pragma unroll
        for (int h = 0; h < 12; ++h) acc[h] += hv * w2[u * 12 + h];
    }
    for (int h = 0; h < 12; ++h) bt[(h << 12) + (i << 6) + j] = acc[h];
}

// ---------- fused window attention: one block = one window, wave = M-tile ----------
#define QKP 40    // q/k row stride (32+8 elems, 80 B: 16B-aligned)
#define VTP 72    // vT row stride (64+8)
#define PBP 72    // P row stride
#define AOP 72    // attn-out row stride

__launch_bounds__(256, 2)
__global__ void win_attn(const float* __restrict__ x,
                         const unsigned short* __restrict__ qkv_wt,
                         const float* __restrict__ qkv_b,
                         const unsigned short* __restrict__ proj_wt,
                         const float* __restrict__ proj_b,
                         const float* __restrict__ bt,
                         float* __restrict__ out) {
    __shared__ unsigned short qls[2][64 * QKP];   // 10240 B (wave-private rows)
    __shared__ unsigned short kls[2][64 * QKP];   // 10240 B
    __shared__ unsigned short vts[2][32 * VTP];   //  9216 B
    __shared__ unsigned short pbs[64 * PBP];      //  9216 B (wave-private rows)
    __shared__ unsigned short aop[64 * AOP];      //  9216 B
                                                  // total 48128 B
    const int tid  = threadIdx.x;
    const int lane = tid & 63;
    const int w    = tid >> 6;     // wave 0..3 — owns tokens [16w,16w+16)
    const int l15  = lane & 15;
    const int quad = lane >> 4;
    const int b    = blockIdx.x;
    const floatx4 zf4 = {0.f, 0.f, 0.f, 0.f};

    // ---- persistent x A-frags for this wave's own 16 rows (convert once) ----
    const float* xr = x + ((size_t)b * 64 + 16 * w + l15) * 384 + quad * 8;
    short8 af[12];
#pragma unroll
    for (int kk = 0; kk < 12; ++kk) {
        const float4 u0 = *reinterpret_cast<const float4*>(xr + kk * 32);
        const float4 u1 = *reinterpret_cast<const float4*>(xr + kk * 32 + 4);
        short8 t;
        t[0] = (short)f2bf(u0.x); t[1] = (short)f2bf(u0.y);
        t[2] = (short)f2bf(u0.z); t[3] = (short)f2bf(u0.w);
        t[4] = (short)f2bf(u1.x); t[5] = (short)f2bf(u1.y);
        t[6] = (short)f2bf(u1.z); t[7] = (short)f2bf(u1.w);
        af[kk] = t;
    }

    // ---- persistent proj accumulators: wave owns out cols [96w, 96w+96) ----
    floatx4 acc2[6][4];
#pragma unroll
    for (int j = 0; j < 6; ++j)
#pragma unroll
        for (int m = 0; m < 4; ++m) acc2[j][m] = zf4;

#pragma unroll 1
    for (int hp = 0; hp < 6; ++hp) {
        // ======== B1: QKV for heads 2hp, 2hp+1 — wave's own M-tile ========
#pragma unroll
        for (int hi = 0; hi < 2; ++hi) {
            const int h = 2 * hp + hi;
            floatx4 qa[2], ka[2], va[2];
#pragma unroll
            for (int t = 0; t < 2; ++t) { qa[t] = zf4; ka[t] = zf4; va[t] = zf4; }
            const unsigned short* wb = qkv_wt + ((size_t)h * 32 + l15) * 384 + quad * 8;
#pragma unroll
            for (int kk = 0; kk < 12; ++kk) {
                const short8 bq0 = *reinterpret_cast<const short8*>(wb + kk * 32);
                const short8 bq1 = *reinterpret_cast<const short8*>(wb + 6144 + kk * 32);
                const short8 bk0 = *reinterpret_cast<const short8*>(wb + 147456 + kk * 32);
                const short8 bk1 = *reinterpret_cast<const short8*>(wb + 147456 + 6144 + kk * 32);
                const short8 bv0 = *reinterpret_cast<const short8*>(wb + 294912 + kk * 32);
                const short8 bv1 = *reinterpret_cast<const short8*>(wb + 294912 + 6144 + kk * 32);
                qa[0] = __builtin_amdgcn_mfma_f32_16x16x32_bf16(af[kk], bq0, qa[0], 0, 0, 0);
                qa[1] = __builtin_amdgcn_mfma_f32_16x16x32_bf16(af[kk], bq1, qa[1], 0, 0, 0);
                ka[0] = __builtin_amdgcn_mfma_f32_16x16x32_bf16(af[kk], bk0, ka[0], 0, 0, 0);
                ka[1] = __builtin_amdgcn_mfma_f32_16x16x32_bf16(af[kk], bk1, ka[1], 0, 0, 0);
                va[0] = __builtin_amdgcn_mfma_f32_16x16x32_bf16(af[kk], bv0, va[0], 0, 0, 0);
                va[1] = __builtin_amdgcn_mfma_f32_16x16x32_bf16(af[kk], bv1, va[1], 0, 0, 0);
            }
            // epilogue: +bias; q,k row-major (wave-private rows); v transposed
#pragma unroll
            for (int t = 0; t < 2; ++t) {
                const int col = h * 32 + t * 16 + l15;
                const float bq = qkv_b[col];
                const float bk = qkv_b[384 + col];
                const float bv = qkv_b[768 + col];
#pragma unroll
                for (int r = 0; r < 4; ++r) {
                    const int tok = 16 * w + 4 * quad + r;
                    qls[hi][tok * QKP + t * 16 + l15] = f2bf(qa[t][r] + bq);
                    kls[hi][tok * QKP + t * 16 + l15] = f2bf(ka[t][r] + bk);
                }
                uint2 pk;
                pk.x = (unsigned)f2bf(va[t][0] + bv) | ((unsigned)f2bf(va[t][1] + bv) << 16);
                pk.y = (unsigned)f2bf(va[t][2] + bv) | ((unsigned)f2bf(va[t][3] + bv) << 16);
                *reinterpret_cast<uint2*>(
                    &vts[hi][(t * 16 + l15) * VTP + 16 * w + 4 * quad]) = pk;
            }
        }
        __syncthreads();   // barrier 1: kls/vts cross-wave

        // ======== B2+B3 per head: S, softmax, P@V — all wave-private rows ========
#pragma unroll
        for (int hi = 0; hi < 2; ++hi) {
            const int h = 2 * hp + hi;
            const short8 aq = *reinterpret_cast<const short8*>(
                &qls[hi][(16 * w + l15) * QKP + quad * 8]);
            floatx4 s4[4];
#pragma unroll
            for (int c = 0; c < 4; ++c) {
                const short8 bk = *reinterpret_cast<const short8*>(
                    &kls[hi][(16 * c + l15) * QKP + quad * 8]);
                s4[c] = __builtin_amdgcn_mfma_f32_16x16x32_bf16(aq, bk, zf4, 0, 0, 0);
            }
            const float* bth = bt + ((size_t)h << 12);
            float rs[4];
#pragma unroll
            for (int r = 0; r < 4; ++r) {
                const int n = 16 * w + 4 * quad + r;
#pragma unroll
                for (int c = 0; c < 4; ++c)
                    s4[c][r] = s4[c][r] * SCALE + bth[(n << 6) + 16 * c + l15];
                float m0 = fmaxf(fmaxf(s4[0][r], s4[1][r]), fmaxf(s4[2][r], s4[3][r]));
#pragma unroll
                for (int sh = 1; sh < 16; sh <<= 1) m0 = fmaxf(m0, __shfl_xor(m0, sh, 16));
                float p0 = 0.f;
#pragma unroll
                for (int c = 0; c < 4; ++c) {
                    float p = __expf(s4[c][r] - m0);
                    s4[c][r] = p;
                    p0 += p;
                }
#pragma unroll
                for (int sh = 1; sh < 16; sh <<= 1) p0 += __shfl_xor(p0, sh, 16);
                rs[r] = 1.f / p0;
#pragma unroll
                for (int c = 0; c < 4; ++c)
                    pbs[n * PBP + 16 * c + l15] = f2bf(s4[c][r]);   // wave-private rows
            }
            __asm__ volatile("" ::: "memory");  // order pbs writes before reads (same wave)

            const short8 ap0 = *reinterpret_cast<const short8*>(
                &pbs[(16 * w + l15) * PBP + quad * 8]);
            const short8 ap1 = *reinterpret_cast<const short8*>(
                &pbs[(16 * w + l15) * PBP + 32 + quad * 8]);
#pragma unroll
            for (int t = 0; t < 2; ++t) {
                floatx4 o = zf4;
                const short8 bv0 = *reinterpret_cast<const short8*>(
                    &vts[hi][(16 * t + l15) * VTP + quad * 8]);
                const short8 bv1 = *reinterpret_cast<const short8*>(
                    &vts[hi][(16 * t + l15) * VTP + 32 + quad * 8]);
                o = __builtin_amdgcn_mfma_f32_16x16x32_bf16(ap0, bv0, o, 0, 0, 0);
                o = __builtin_amdgcn_mfma_f32_16x16x32_bf16(ap1, bv1, o, 0, 0, 0);
#pragma unroll
                for (int r = 0; r < 4; ++r)
                    aop[(16 * w + 4 * quad + r) * AOP + hi * 32 + 16 * t + l15] =
                        f2bf(o[r] * rs[r]);
            }
        }
        __syncthreads();   // barrier 2: aop cross-wave

        // ======== proj partial: out[:, 96w:96w+96] += aop @ proj_w[64hp:64hp+64, :] ====
        short8 ap2[4][2];
#pragma unroll
        for (int m = 0; m < 4; ++m) {
            ap2[m][0] = *reinterpret_cast<const short8*>(&aop[(16 * m + l15) * AOP + quad * 8]);
            ap2[m][1] = *reinterpret_cast<const short8*>(&aop[(16 * m + l15) * AOP + 32 + quad * 8]);
        }
#pragma unroll
        for (int j = 0; j < 6; ++j) {
            const unsigned short* pw =
                proj_wt + ((size_t)(96 * w + 16 * j + l15)) * 384 + hp * 64 + quad * 8;
            const short8 b0 = *reinterpret_cast<const short8*>(pw);
            const short8 b1 = *reinterpret_cast<const short8*>(pw + 32);
#pragma unroll
            for (int m = 0; m < 4; ++m) {
                acc2[j][m] = __builtin_amdgcn_mfma_f32_16x16x32_bf16(ap2[m][0], b0, acc2[j][m], 0, 0, 0);
                acc2[j][m] = __builtin_amdgcn_mfma_f32_16x16x32_bf16(ap2[m][1], b1, acc2[j][m], 0, 0, 0);
            }
        }
        // no barrier needed: next write to aop (B3 of hp+1) is after barrier 1 of hp+1
    }

    // ======== epilogue: out = acc2 + proj_b ========
    float* ob = out + (size_t)b * (64 * 384);
#pragma unroll
    for (int j = 0; j < 6; ++j) {
        const int col = 96 * w + 16 * j + l15;
        const float pb = proj_b[col];
#pragma unroll
        for (int m = 0; m < 4; ++m)
#pragma unroll
            for (int r = 0; r < 4; ++r)
                ob[(16 * m + 4 * quad + r) * 384 + col] = acc2[j][m][r] + pb;
    }
}

extern "C" void kernel_launch(void* const* d_in, const int* in_sizes, int n_in,
                              void* d_out, int out_size, void* d_ws, size_t ws_size,
                              hipStream_t stream) {
    const float* x      = (const float*)d_in[0];
    const float* qkv_w  = (const float*)d_in[1];
    const float* qkv_b  = (const float*)d_in[2];
    const float* proj_w = (const float*)d_in[3];
    const float* proj_b = (const float*)d_in[4];
    const float* mlp_w1 = (const float*)d_in[5];
    const float* mlp_b1 = (const float*)d_in[6];
    const float* mlp_w2 = (const float*)d_in[7];
    const float* mlp_b2 = (const float*)d_in[8];
    float* out = (float*)d_out;

    unsigned short* qkv_wt  = (unsigned short*)d_ws;              // 1152*384 bf16
    unsigned short* proj_wt = qkv_wt + 1152 * 384;                // 384*384 bf16
    float*          bt      = (float*)(proj_wt + 384 * 384);      // 12*64*64 fp32

    transpose_bf16<<<dim3(36, 12), 256, 0, stream>>>(qkv_w, qkv_wt, 384, 1152);
    transpose_bf16<<<dim3(12, 12), 256, 0, stream>>>(proj_w, proj_wt, 384, 384);
    prep_bias<<<64, 64, 0, stream>>>(mlp_w1, mlp_b1, mlp_w2, mlp_b2, bt);
    win_attn<<<2048, 256, 0, stream>>>(x, qkv_wt, qkv_b, proj_wt, proj_b, bt, out);
}